// Round 1
// baseline (324.634 us; speedup 1.0000x reference)
//
#include <hip/hip_runtime.h>
#include <hip/hip_bf16.h>
#include <math.h>

#define N_PTS 8192
#define M_PTS 2048
#define KLAST 10
#define VARS 3
#define OUTD 32
#define D1 80
#define D2 80
#define PB 8          // points per agg block -> 1024 blocks, 4 blocks/CU
#define LPTS 4        // output points per last block -> 512 blocks
#define NT 512        // agg: 8 waves per block
#define NWAVES 8
#define NTL 256       // last: 4 waves per block -> 8 blocks/CU
#define NWL 4
#define TPCH 104      // Tb row pitch in bf16 (208 B; stride-52 dwords -> 2-way banks)
#define W0P 72        // W0 K-pitch (K=64 used: feats 0..32, pos 32..36, pad ..64)
#define W1P 104       // W1/W2 K-pitch (K=80 padded to 96)
#define RP 32         // f0b/f1b record pitch in bf16 (64 B = ONE cache line)
#define W0SZ (D1 * W0P)              // 5760
#define W1SZ (D1 * W1P)              // 8320
#define W2SZ (OUTD * W1P)            // 3328
#define WPACK (W0SZ + W1SZ + W2SZ)   // 17408 bf16 elems per weight set

typedef float f4 __attribute__((ext_vector_type(4)));
typedef short bf16x8 __attribute__((ext_vector_type(8)));

// lean inf-safe tanh-gelu: gelu = x - x*rcp(exp2(x*(A+B*x^2))+1); err ~3e-4.
__device__ __forceinline__ float gelu_f(float x) {
    float x2 = x * x;
    float s = x * __builtin_fmaf(0.1029418f, x2, 2.3022083f);
    float u = __builtin_amdgcn_exp2f(s);
    float r = __builtin_amdgcn_rcpf(u + 1.0f);
    return __builtin_fmaf(-x, r, x);
}
__device__ __forceinline__ unsigned short f2bf(float x) {
    unsigned int u = __float_as_uint(x);
    u += 0x7FFF + ((u >> 16) & 1);
    return (unsigned short)(u >> 16);
}
__device__ __forceinline__ float bf2f(unsigned short h) {
    return __uint_as_float(((unsigned int)h) << 16);
}
// packed RNE f32x2 -> bf16x2 (v_cvt_pk_bf16_f32 on gfx950)
__device__ __forceinline__ int pk2(float a, float b) {
    __hip_bfloat162 h = __float22bfloat162_rn(float2{a, b});
    int r; __builtin_memcpy(&r, &h, 4); return r;
}

// One-time pack: single-bf16 weights transposed [col][k], K zero-padded, in
// the exact per-lane MFMA fragment layout. Consumers read fragments straight
// from global (coalesced 16B/lane, L1/L2-resident 35 KB set). W0 k-order
// REORDERED: k 0..31 <- W0g rows 4..35 (features), k 32..35 <- rows 0..3.
__device__ __forceinline__ void pack_weights(
    const float* __restrict__ W0g, const float* __restrict__ W1g,
    const float* __restrict__ W2g, unsigned short* __restrict__ wp, int t)
{
    for (int idx = t; idx < W0SZ; idx += 256) {
        int col = idx / W0P, k = idx - col * W0P;
        float w = (k < 32) ? W0g[(k + 4) * D1 + col]
                           : ((k < 36) ? W0g[(k - 32) * D1 + col] : 0.0f);
        wp[idx] = f2bf(w);
    }
    for (int idx = t; idx < W1SZ; idx += 256) {
        int col = idx / W1P, k = idx - col * W1P;
        wp[W0SZ + idx] = f2bf((k < D2) ? W1g[k * D1 + col] : 0.0f);
    }
    for (int idx = t; idx < W2SZ; idx += 256) {
        int col = idx / W1P, k = idx - col * W1P;
        wp[W0SZ + W1SZ + idx] = f2bf((k < D2) ? W2g[k * OUTD + col] : 0.0f);
    }
}

// Per-wave 16-row chunk MLP. cb loops stay unroll-1 (widened-live-set attempts
// spilled under the reg cap — R2/R3, R6/R7, R9, R14), but each loop now runs a
// ROTATION PREFETCH: next cb's weight fragments + bias are issued while the
// current cb's MFMA+gelu execute, so the per-cb L1-miss round-trip (35 KB
// weight set > 32 KB L1) is hidden instead of serially exposed. At layer
// boundaries the next layer's cb0 fragments ride over the LDS turnaround
// (vmcnt vs lgkmcnt are independent). Tripwire: FETCH/WRITE (spill).
__device__ __forceinline__ void mlp_chunk(
    int4 featsi, int4 posfi, unsigned short* Trow,
    const unsigned short* __restrict__ W0h,
    const unsigned short* __restrict__ W1h,
    const unsigned short* __restrict__ W2h,
    const float* bs, int lm, int quad)
{
    bf16x8 b1f0 = *(bf16x8*)&featsi;
    bf16x8 b1f1 = *(bf16x8*)&posfi;
    const unsigned short* w0base = &W0h[lm * W0P + quad * 8];
    const unsigned short* w1base = &W1h[lm * W1P + quad * 8];
    const unsigned short* w2base = &W2h[lm * W1P + quad * 8];
    // ---- L1: K=64 (feats+pos+pad) -> 80, gelu ----
    bf16x8 pa0 = *(const bf16x8*)&w0base[0];
    bf16x8 pa1 = *(const bf16x8*)&w0base[32];
    f4 pb = *(const f4*)&bs[quad * 4];
#pragma unroll 1
    for (int cb = 0; cb < 5; ++cb) {
        bf16x8 a0 = pa0, a1 = pa1;
        const unsigned short* nw = (cb < 4) ? &w0base[(cb + 1) * 16 * W0P] : w1base;
        pa0 = *(const bf16x8*)&nw[0];
        pa1 = *(const bf16x8*)&nw[32];
        f4 acc = pb;
        pb = *(const f4*)&bs[((cb < 4) ? (cb + 1) * 16 : 80) + quad * 4];
        acc = __builtin_amdgcn_mfma_f32_16x16x32_bf16(a0, b1f0, acc, 0, 0, 0);
        acc = __builtin_amdgcn_mfma_f32_16x16x32_bf16(a1, b1f1, acc, 0, 0, 0);
        *(int2*)&Trow[cb * 16 + quad * 4] =
            make_int2(pk2(gelu_f(acc.x), gelu_f(acc.y)),
                      pk2(gelu_f(acc.z), gelu_f(acc.w)));
    }
    // ---- L2: 80(pad 96) -> 80, gelu ----
    bf16x8 pa2 = *(const bf16x8*)&w1base[64];
    bf16x8 b2f0 = *(const bf16x8*)&Trow[quad * 8];
    bf16x8 b2f1 = *(const bf16x8*)&Trow[32 + quad * 8];
    bf16x8 b2f2 = *(const bf16x8*)&Trow[64 + quad * 8];
#pragma unroll 1
    for (int cb = 0; cb < 5; ++cb) {
        bf16x8 h0 = pa0, h1 = pa1, h2 = pa2;
        const unsigned short* nw = (cb < 4) ? &w1base[(cb + 1) * 16 * W1P] : w2base;
        pa0 = *(const bf16x8*)&nw[0];
        pa1 = *(const bf16x8*)&nw[32];
        pa2 = *(const bf16x8*)&nw[64];
        f4 acc = pb;
        pb = *(const f4*)&bs[((cb < 4) ? 80 + (cb + 1) * 16 : 160) + quad * 4];
        acc = __builtin_amdgcn_mfma_f32_16x16x32_bf16(h0, b2f0, acc, 0, 0, 0);
        acc = __builtin_amdgcn_mfma_f32_16x16x32_bf16(h1, b2f1, acc, 0, 0, 0);
        acc = __builtin_amdgcn_mfma_f32_16x16x32_bf16(h2, b2f2, acc, 0, 0, 0);
        *(int2*)&Trow[cb * 16 + quad * 4] =
            make_int2(pk2(gelu_f(acc.x), gelu_f(acc.y)),
                      pk2(gelu_f(acc.z), gelu_f(acc.w)));
    }
    // ---- L3: 80(pad 96) -> 32, fp32 out at Trow floats [0..32) ----
    bf16x8 b3f0 = *(const bf16x8*)&Trow[quad * 8];
    bf16x8 b3f1 = *(const bf16x8*)&Trow[32 + quad * 8];
    bf16x8 b3f2 = *(const bf16x8*)&Trow[64 + quad * 8];
    float* po = (float*)Trow;
#pragma unroll 1
    for (int cb = 0; cb < 2; ++cb) {
        bf16x8 h0 = pa0, h1 = pa1, h2 = pa2;
        if (cb == 0) {
            const unsigned short* nw = &w2base[16 * W1P];
            pa0 = *(const bf16x8*)&nw[0];
            pa1 = *(const bf16x8*)&nw[32];
            pa2 = *(const bf16x8*)&nw[64];
        }
        f4 acc = pb;
        if (cb == 0) pb = *(const f4*)&bs[176 + quad * 4];
        acc = __builtin_amdgcn_mfma_f32_16x16x32_bf16(h0, b3f0, acc, 0, 0, 0);
        acc = __builtin_amdgcn_mfma_f32_16x16x32_bf16(h1, b3f1, acc, 0, 0, 0);
        acc = __builtin_amdgcn_mfma_f32_16x16x32_bf16(h2, b3f2, acc, 0, 0, 0);
        *(f4*)&po[cb * 16 + quad * 4] = acc;
    }
}

// ---- merged projection + scan + weight-pack ----
__global__ __launch_bounds__(256) void proj_scan_kernel(
    const float* __restrict__ inp, const float* __restrict__ grid_in,
    const float* __restrict__ W0, const float* __restrict__ b0,
    const float* __restrict__ W1, const float* __restrict__ b1,
    unsigned short* __restrict__ f0b, int* __restrict__ posb,
    const int* __restrict__ counts, int* __restrict__ offsets,
    const float* __restrict__ i0W0, const float* __restrict__ i0W1,
    const float* __restrict__ i0W2, unsigned short* __restrict__ wpack0,
    const float* __restrict__ i1W0, const float* __restrict__ i1W1,
    const float* __restrict__ i1W2, unsigned short* __restrict__ wpack1)
{
    const int t = threadIdx.x;
    if (blockIdx.x == 769) { pack_weights(i0W0, i0W1, i0W2, wpack0, t); return; }
    if (blockIdx.x == 770) { pack_weights(i1W0, i1W1, i1W2, wpack1, t); return; }
    if (blockIdx.x == 768) {
        __shared__ int ws2[4], wx2[4];
        const int lane = t & 63, wave = t >> 6;
        int4 a[8];
#pragma unroll
        for (int i = 0; i < 8; ++i) a[i] = ((const int4*)counts)[t * 8 + i];
        int s = 0;
#pragma unroll
        for (int i = 0; i < 8; ++i) s += a[i].x + a[i].y + a[i].z + a[i].w;
        int x = s;
#pragma unroll
        for (int d = 1; d < 64; d <<= 1) {
            int y = __shfl_up(x, d);
            if (lane >= d) x += y;
        }
        if (lane == 63) ws2[wave] = x;
        __syncthreads();
        if (t == 0) {
            wx2[0] = 0;
            wx2[1] = ws2[0];
            wx2[2] = ws2[0] + ws2[1];
            wx2[3] = ws2[0] + ws2[1] + ws2[2];
        }
        __syncthreads();
        int base = wx2[wave] + (x - s);
#pragma unroll
        for (int i = 0; i < 8; ++i) {
            int4 c = a[i];
            int4 o;
            o.x = base; base += c.x;
            o.y = base; base += c.y;
            o.z = base; base += c.z;
            o.w = base; base += c.w;
            ((int4*)offsets)[t * 8 + i] = o;
        }
        return;
    }
    __shared__ float W0s[8 * 64];
    __shared__ float W1s[64 * OUTD];
    __shared__ float xs[32 * 8];
    __shared__ float H[32 * 64];
    const int r0 = blockIdx.x * 32;
    for (int idx = t; idx < 512; idx += 256) W0s[idx] = W0[idx];
    for (int idx = t; idx < 64 * OUTD; idx += 256) W1s[idx] = W1[idx];
    xs[t] = inp[r0 * 8 + t];
    if (t < 32) {
        int row = r0 + t, n = row / 3;
        posb[n] = pk2(grid_in[2 * n], grid_in[2 * n + 1]);  // dup writes benign
    }
    __syncthreads();
#pragma unroll 1
    for (int p = 0; p < 8; ++p) {
        int o = t + 256 * p, r = o >> 6, col = o & 63;
        float s = b0[col];
#pragma unroll
        for (int k = 0; k < 8; ++k) s += xs[r * 8 + k] * W0s[k * 64 + col];
        H[o] = gelu_f(s);
    }
    __syncthreads();
#pragma unroll 1
    for (int p = 0; p < 4; ++p) {
        int o = t + 256 * p, r = o >> 5, c = o & 31;
        float s = b1[c];
#pragma unroll 8
        for (int k = 0; k < 64; ++k) s += H[r * 64 + k] * W1s[k * OUTD + c];
        int row = r0 + r;
        int n = row / 3, v = row - n * 3;
        f0b[((size_t)(v << 13) + n) * RP + c] = f2bf(s);
    }
}

// ---- edge MLP + owner-computes segment mean ----
// 8 waves x 512 thr, PB=8 -> 1024 blocks, 4 blocks/CU = 32 waves/CU.
// Gather pipeline is 2-deep: index load (nbr_index) issued 2 iterations
// ahead, record gather (f0b) 1 ahead — the dependent index->record chain is
// never exposed in steady state (it was serially exposed per chunk before).
__global__ __launch_bounds__(512, 8) void agg_kernel(
    const float* __restrict__ grid_in, const unsigned short* __restrict__ f0b,
    const int* __restrict__ posb,
    const int* __restrict__ nbr_index, const int* __restrict__ offsets,
    const int* __restrict__ counts,
    const unsigned short* __restrict__ wpack,
    const float* __restrict__ b0g, const float* __restrict__ b1g,
    const float* __restrict__ b2g,
    unsigned short* __restrict__ f1b)
{
    __shared__ __attribute__((aligned(16))) unsigned short Tb[NWAVES * 16 * TPCH];
    __shared__ __attribute__((aligned(16))) float bs[192];
    __shared__ __attribute__((aligned(16))) float accH[VARS * PB * 32];
    __shared__ int offs[PB + 1];
    __shared__ int px2b[PB];
    __shared__ float invb[PB];

    const unsigned short* W0h = wpack;
    const unsigned short* W1h = wpack + W0SZ;
    const unsigned short* W2h = wpack + W0SZ + W1SZ;

    const int t = threadIdx.x;
    const int lane = t & 63, wave = t >> 6;
    const int lm = lane & 15, quad = lane >> 4;
    const int p0 = blockIdx.x * PB;

    for (int idx = t; idx < 192; idx += NT)
        bs[idx] = (idx < 80) ? b0g[idx] : (idx < 160 ? b1g[idx - 80] : b2g[idx - 160]);
    if (t < PB) {
        offs[t] = offsets[p0 + t];
        int c = counts[p0 + t];
        invb[t] = 1.0f / (float)(c > 1 ? c : 1);
        px2b[t] = pk2(grid_in[2 * (p0 + t)], grid_in[2 * (p0 + t) + 1]);
    }
    if (t == PB) offs[PB] = offsets[p0 + PB - 1] + counts[p0 + PB - 1];
    for (int idx = t; idx < VARS * PB * 32; idx += NT) accH[idx] = 0.0f;
    __syncthreads();

    // zero persistent pad [80..96) of this wave's 16 rows (never rewritten)
    unsigned short* TbW = Tb + (wave * 16) * TPCH;
    if (lane < 32)
        *(int4*)(TbW + (lane >> 1) * TPCH + 80 + (lane & 1) * 8) = make_int4(0, 0, 0, 0);

    const int e0 = offs[0];
    const int cntT = offs[PB] - e0;
    const int Rb = VARS * cntT;
    const int nch = (Rb + 15) >> 4;

    unsigned short* Trow = TbW + lm * TPCH;

    // stage A: index fetch (key + nbr j) — issues one global load
    auto fetch_index = [&](int ch2, int& key, int& j) {
        key = -1; j = 0;
        if (ch2 < nch) {
            int myrow = (ch2 << 4) + lm;
            if (myrow < Rb) {
                int myv = (myrow >= 2 * cntT) ? 2 : ((myrow >= cntT) ? 1 : 0);
                int e = e0 + myrow - myv * cntT;
                int lp = 0;
#pragma unroll
                for (int l = 1; l < PB; ++l) lp += (e >= offs[l]);
                key = myv * PB + lp;
                j = nbr_index[e];
            }
        }
    };
    // stage B: record gather — j must be resident (loaded 1 iteration earlier)
    auto fetch_record = [&](int key, int j, int4& feats, int4& posf) {
        feats = make_int4(0, 0, 0, 0); posf = make_int4(0, 0, 0, 0);
        if (key >= 0) {
            int v = key >> 3, lp = key & 7;   // PB == 8
            feats = ((const int4*)(f0b + ((size_t)(v << 13) + j) * RP))[quad];
            if (quad == 0) posf = make_int4(posb[j], px2b[lp], 0, 0);
        }
    };

    int keyA, jA, keyB, jB;
    fetch_index(wave, keyA, jA);
    fetch_index(wave + NWAVES, keyB, jB);
    int4 featsA, posfA;
    fetch_record(keyA, jA, featsA, posfA);

    for (int ch = wave; ch < nch; ch += NWAVES) {
        int ckey = keyA; int4 cf = featsA, cp = posfA;
        keyA = keyB; jA = jB;
        fetch_index(ch + 2 * NWAVES, keyB, jB);       // index 2 ahead
        fetch_record(keyA, jA, featsA, posfA);        // record 1 ahead
        mlp_chunk(cf, cp, Trow, W0h, W1h, W2h, bs, lm, quad);
        // keyed reduction of this wave's 16 rows into block accumulator
        int col = lane & 31, eo = lane >> 5;
#pragma unroll 1
        for (int e2 = eo; e2 < 16; e2 += 2) {
            int k = __shfl(ckey, e2);
            if (k >= 0)
                atomicAdd(&accH[k * 32 + col], ((const float*)(TbW + e2 * TPCH))[col]);
        }
    }
    __syncthreads();
    for (int idx = t; idx < VARS * PB * OUTD; idx += NT) {
        int key = idx >> 5, c = idx & 31;
        int v = key >> 3, lp = key & 7;     // PB == 8
        size_t rec = ((size_t)(v << 13) + p0 + lp) * RP;
        float val = accH[key * 32 + c] * invb[lp] + bf2f(f0b[rec + c]);
        f1b[rec + c] = f2bf(val);
    }
}

// ---- kNN MLP + mean over K ----
// RE-GRIDDED: 256 thr / 4 waves, LPTS=4 -> 512 blocks, 8 blocks/CU =
// 32 waves/CU (was 2 blocks/CU = 16 waves) and 2 chunks/wave (was 1) —
// the old shape had no TLP to hide the gather+weight latency chains.
__global__ __launch_bounds__(256, 8) void last_kernel(
    const unsigned short* __restrict__ f1b, const int* __restrict__ posb,
    const float* __restrict__ grid_out,
    const int* __restrict__ nbr_last,
    const unsigned short* __restrict__ wpack,
    const float* __restrict__ b0g, const float* __restrict__ b1g,
    const float* __restrict__ b2g,
    float* __restrict__ out)
{
    __shared__ __attribute__((aligned(16))) unsigned short Tb[NWL * 16 * TPCH];
    __shared__ __attribute__((aligned(16))) float bs[192];
    __shared__ __attribute__((aligned(16))) float accH[LPTS * VARS * 32];
    __shared__ int pxo2b[LPTS];

    const unsigned short* W0h = wpack;
    const unsigned short* W1h = wpack + W0SZ;
    const unsigned short* W2h = wpack + W0SZ + W1SZ;

    const int t = threadIdx.x;
    const int lane = t & 63, wave = t >> 6;
    const int lm = lane & 15, quad = lane >> 4;
    const int m0 = blockIdx.x * LPTS;

    for (int idx = t; idx < 192; idx += NTL)
        bs[idx] = (idx < 80) ? b0g[idx] : (idx < 160 ? b1g[idx - 80] : b2g[idx - 160]);
    if (t < LPTS)
        pxo2b[t] = pk2(grid_out[2 * (m0 + t)], grid_out[2 * (m0 + t) + 1]);
    for (int idx = t; idx < LPTS * VARS * 32; idx += NTL) accH[idx] = 0.0f;
    __syncthreads();
    unsigned short* TbW = Tb + (wave * 16) * TPCH;
    if (lane < 32)
        *(int4*)(TbW + (lane >> 1) * TPCH + 80 + (lane & 1) * 8) = make_int4(0, 0, 0, 0);

    const int Rb = LPTS * VARS * KLAST;   // 120
    const int nch = (Rb + 15) >> 4;       // 8
    unsigned short* Trow = TbW + lm * TPCH;

    auto fetch_index = [&](int ch2, int& key, int& j) {
        key = -1; j = 0;
        if (ch2 < nch) {
            int myrow = (ch2 << 4) + lm;
            if (myrow < Rb) {
                int lp = myrow / 30, rr = myrow - lp * 30;
                int v = rr / KLAST, kk = rr - v * KLAST;
                j = nbr_last[(m0 + lp) * KLAST + kk];
                key = lp * VARS + v;
            }
        }
    };
    auto fetch_record = [&](int key, int j, int4& feats, int4& posf) {
        feats = make_int4(0, 0, 0, 0); posf = make_int4(0, 0, 0, 0);
        if (key >= 0) {
            int lp = key / VARS, v = key - lp * VARS;
            feats = ((const int4*)(f1b + ((size_t)(v << 13) + j) * RP))[quad];
            if (quad == 0) posf = make_int4(posb[j], pxo2b[lp], 0, 0);
        }
    };

    int keyA, jA, keyB, jB;
    fetch_index(wave, keyA, jA);
    fetch_index(wave + NWL, keyB, jB);
    int4 featsA, posfA;
    fetch_record(keyA, jA, featsA, posfA);

    for (int ch = wave; ch < nch; ch += NWL) {
        int ckey = keyA; int4 cf = featsA, cp = posfA;
        keyA = keyB; jA = jB;
        fetch_index(ch + 2 * NWL, keyB, jB);
        fetch_record(keyA, jA, featsA, posfA);
        mlp_chunk(cf, cp, Trow, W0h, W1h, W2h, bs, lm, quad);
        int col = lane & 31, eo = lane >> 5;
#pragma unroll 1
        for (int e2 = eo; e2 < 16; e2 += 2) {
            int k = __shfl(ckey, e2);
            if (k >= 0)
                atomicAdd(&accH[k * 32 + col], ((const float*)(TbW + e2 * TPCH))[col]);
        }
    }
    __syncthreads();
    for (int idx = t; idx < LPTS * VARS * OUTD; idx += NTL) {
        int key = idx >> 5, c = idx & 31;
        int lp = key / VARS, v = key - lp * VARS;
        out[((size_t)(m0 + lp) * VARS + v) * OUTD + c] = accH[key * 32 + c] * (1.0f / KLAST);
    }
}

extern "C" void kernel_launch(void* const* d_in, const int* in_sizes, int n_in,
                              void* d_out, int out_size, void* d_ws, size_t ws_size,
                              hipStream_t stream) {
    const float* inp      = (const float*)d_in[0];
    const float* grid_in  = (const float*)d_in[1];
    const float* grid_out = (const float*)d_in[2];
    const float* pW0 = (const float*)d_in[3];
    const float* pb0 = (const float*)d_in[4];
    const float* pW1 = (const float*)d_in[5];
    const float* pb1 = (const float*)d_in[6];
    const float* i0W0 = (const float*)d_in[7];
    const float* i0b0 = (const float*)d_in[8];
    const float* i0W1 = (const float*)d_in[9];
    const float* i0b1 = (const float*)d_in[10];
    const float* i0W2 = (const float*)d_in[11];
    const float* i0b2 = (const float*)d_in[12];
    const float* i1W0 = (const float*)d_in[13];
    const float* i1b0 = (const float*)d_in[14];
    const float* i1W1 = (const float*)d_in[15];
    const float* i1b1 = (const float*)d_in[16];
    const float* i1W2 = (const float*)d_in[17];
    const float* i1b2 = (const float*)d_in[18];
    const int* nbr_index  = (const int*)d_in[19];
    const int* nbr_counts = (const int*)d_in[21];
    const int* nbr_last   = (const int*)d_in[22];

    unsigned short* f0b = (unsigned short*)d_ws;                      // 3*8192*32 bf16
    unsigned short* f1b = f0b + (size_t)VARS * N_PTS * RP;            // 3*8192*32 bf16
    int* offsets = (int*)(f1b + (size_t)VARS * N_PTS * RP);           // N ints
    int* posb    = offsets + N_PTS;                                   // N ints (bf16x2)
    unsigned short* wpack0 = (unsigned short*)(posb + N_PTS);         // 17408 bf16
    unsigned short* wpack1 = wpack0 + WPACK;                          // 17408 bf16

    proj_scan_kernel<<<771, 256, 0, stream>>>(inp, grid_in, pW0, pb0, pW1, pb1,
                                              f0b, posb, nbr_counts, offsets,
                                              i0W0, i0W1, i0W2, wpack0,
                                              i1W0, i1W1, i1W2, wpack1);
    agg_kernel<<<N_PTS / PB, NT, 0, stream>>>(grid_in, f0b, posb, nbr_index, offsets,
                                              nbr_counts, wpack0,
                                              i0b0, i0b1, i0b2, f1b);
    last_kernel<<<M_PTS / LPTS, NTL, 0, stream>>>(f1b, posb, grid_out, nbr_last, wpack1,
                                                  i1b0, i1b1, i1b2,
                                                  (float*)d_out);
}

// Round 2
// 308.853 us; speedup vs baseline: 1.0511x; 1.0511x over previous
//
#include <hip/hip_runtime.h>
#include <hip/hip_bf16.h>
#include <math.h>

#define N_PTS 8192
#define M_PTS 2048
#define KLAST 10
#define VARS 3
#define OUTD 32
#define D1 80
#define D2 80
#define PB 8          // points per agg block -> 1024 blocks, 4 blocks/CU
#define LPTS 4        // output points per last block -> 512 blocks
#define NT 512        // agg: 8 waves per block
#define NWAVES 8
#define NTL 256       // last: 4 waves per block -> 8 blocks/CU
#define NWL 4
#define TPCH 104      // Tb row pitch in bf16 (208 B; stride-52 dwords -> 2-way banks)
#define RP 32         // f0b/f1b record pitch in bf16 (64 B = ONE cache line)

// Lane-major fragment-packed weights (R2): fragment f = 64 lanes x 8 bf16,
// stored wp[f*512 + lane*8]. Every weight load is base + lane*16B -> ONE
// perfectly coalesced 1KB vector load (16 sequential lines), replacing the
// old row-pitch scatter (64 addrs over ~16-32 lines per load) that saturated
// the per-CU L1/TA pipe (R1 theory: VALU 28%/MFMA 5%/HBM 2% with wall-long
// stalls = invisible-unit bound). Set shrinks to 31.7 KB (~L1-resident).
#define FRAG 512                     // bf16 per fragment (64 lanes x 8)
#define W0F 10                       // L1 frags: 5 cb x 2 kslices
#define W1F 15                       // L2 frags: 5 cb x 3 kslices
#define W2F 6                        // L3 frags: 2 cb x 3 kslices
#define WPACK ((W0F + W1F + W2F) * FRAG)   // 15872 bf16 = 31744 B per set

typedef float f4 __attribute__((ext_vector_type(4)));
typedef short bf16x8 __attribute__((ext_vector_type(8)));

// lean inf-safe tanh-gelu: gelu = x - x*rcp(exp2(x*(A+B*x^2))+1); err ~3e-4.
__device__ __forceinline__ float gelu_f(float x) {
    float x2 = x * x;
    float s = x * __builtin_fmaf(0.1029418f, x2, 2.3022083f);
    float u = __builtin_amdgcn_exp2f(s);
    float r = __builtin_amdgcn_rcpf(u + 1.0f);
    return __builtin_fmaf(-x, r, x);
}
__device__ __forceinline__ unsigned short f2bf(float x) {
    unsigned int u = __float_as_uint(x);
    u += 0x7FFF + ((u >> 16) & 1);
    return (unsigned short)(u >> 16);
}
__device__ __forceinline__ float bf2f(unsigned short h) {
    return __uint_as_float(((unsigned int)h) << 16);
}
// packed RNE f32x2 -> bf16x2 (v_cvt_pk_bf16_f32 on gfx950)
__device__ __forceinline__ int pk2(float a, float b) {
    __hip_bfloat162 h = __float22bfloat162_rn(float2{a, b});
    int r; __builtin_memcpy(&r, &h, 4); return r;
}

// One-time pack into lane-major fragment layout. W0 k-order REORDERED:
// k 0..31 <- W0g rows 4..35 (features), k 32..35 <- rows 0..3 (positions).
__device__ __forceinline__ void pack_weights(
    const float* __restrict__ W0g, const float* __restrict__ W1g,
    const float* __restrict__ W2g, unsigned short* __restrict__ wp, int t)
{
    for (int idx = t; idx < W0F * FRAG; idx += 256) {
        int f = idx >> 9, r = idx & 511;
        int lane = r >> 3, e = r & 7;
        int lm = lane & 15, quad = lane >> 4;
        int cb = f >> 1, ks = f & 1;
        int col = cb * 16 + lm;
        int k = ks * 32 + quad * 8 + e;
        float w = (k < 32) ? W0g[(k + 4) * D1 + col]
                           : ((k < 36) ? W0g[(k - 32) * D1 + col] : 0.0f);
        wp[idx] = f2bf(w);
    }
    for (int idx = t; idx < W1F * FRAG; idx += 256) {
        int f = idx >> 9, r = idx & 511;
        int lane = r >> 3, e = r & 7;
        int lm = lane & 15, quad = lane >> 4;
        int cb = f / 3, ks = f - cb * 3;
        int col = cb * 16 + lm;
        int k = ks * 32 + quad * 8 + e;
        wp[W0F * FRAG + idx] = f2bf((k < D2) ? W1g[k * D1 + col] : 0.0f);
    }
    for (int idx = t; idx < W2F * FRAG; idx += 256) {
        int f = idx >> 9, r = idx & 511;
        int lane = r >> 3, e = r & 7;
        int lm = lane & 15, quad = lane >> 4;
        int cb = f / 3, ks = f - cb * 3;
        int col = cb * 16 + lm;
        int k = ks * 32 + quad * 8 + e;
        wp[(W0F + W1F) * FRAG + idx] = f2bf((k < D2) ? W2g[k * OUTD + col] : 0.0f);
    }
}

// Per-wave 16-row chunk MLP (R0-verified structure; weights from global in
// lane-major fragments: Wl = wpack + lane*8, frag at Wl[f*FRAG]).
// cb loops stay unroll-1 ON PURPOSE — every widened-live-set attempt spilled
// to scratch under the 64-VGPR cap (R2/R3, R6/R7, R9, R14 prior session;
// rotation prefetch in THIS session's R1: FETCH 13->224 MB, WRITE 14->147 MB).
// Tripwire: FETCH/WRITE.
__device__ __forceinline__ void mlp_chunk(
    int4 featsi, int4 posfi, unsigned short* Trow,
    const unsigned short* __restrict__ Wl,
    const float* bs, int lm, int quad)
{
    bf16x8 b1f0 = *(bf16x8*)&featsi;
    bf16x8 b1f1 = *(bf16x8*)&posfi;
    // ---- L1: K=64 (feats+pos+pad) -> 80, gelu ----
#pragma unroll 1
    for (int cb = 0; cb < 5; ++cb) {
        f4 acc = *(const f4*)&bs[cb * 16 + quad * 4];
        bf16x8 a0 = *(const bf16x8*)&Wl[(cb * 2 + 0) * FRAG];
        bf16x8 a1 = *(const bf16x8*)&Wl[(cb * 2 + 1) * FRAG];
        acc = __builtin_amdgcn_mfma_f32_16x16x32_bf16(a0, b1f0, acc, 0, 0, 0);
        acc = __builtin_amdgcn_mfma_f32_16x16x32_bf16(a1, b1f1, acc, 0, 0, 0);
        *(int2*)&Trow[cb * 16 + quad * 4] =
            make_int2(pk2(gelu_f(acc.x), gelu_f(acc.y)),
                      pk2(gelu_f(acc.z), gelu_f(acc.w)));
    }
    // ---- L2: 80(pad 96) -> 80, gelu ----
    bf16x8 b2f[3];
    b2f[0] = *(const bf16x8*)&Trow[quad * 8];
    b2f[1] = *(const bf16x8*)&Trow[32 + quad * 8];
    b2f[2] = *(const bf16x8*)&Trow[64 + quad * 8];
#pragma unroll 1
    for (int cb = 0; cb < 5; ++cb) {
        f4 acc = *(const f4*)&bs[80 + cb * 16 + quad * 4];
        const unsigned short* wh = &Wl[(W0F + cb * 3) * FRAG];
        bf16x8 h0 = *(const bf16x8*)&wh[0];
        bf16x8 h1 = *(const bf16x8*)&wh[FRAG];
        bf16x8 h2 = *(const bf16x8*)&wh[2 * FRAG];
        acc = __builtin_amdgcn_mfma_f32_16x16x32_bf16(h0, b2f[0], acc, 0, 0, 0);
        acc = __builtin_amdgcn_mfma_f32_16x16x32_bf16(h1, b2f[1], acc, 0, 0, 0);
        acc = __builtin_amdgcn_mfma_f32_16x16x32_bf16(h2, b2f[2], acc, 0, 0, 0);
        *(int2*)&Trow[cb * 16 + quad * 4] =
            make_int2(pk2(gelu_f(acc.x), gelu_f(acc.y)),
                      pk2(gelu_f(acc.z), gelu_f(acc.w)));
    }
    // ---- L3: 80(pad 96) -> 32, fp32 out at Trow floats [0..32) ----
    bf16x8 b3f[3];
    b3f[0] = *(const bf16x8*)&Trow[quad * 8];
    b3f[1] = *(const bf16x8*)&Trow[32 + quad * 8];
    b3f[2] = *(const bf16x8*)&Trow[64 + quad * 8];
    float* po = (float*)Trow;
#pragma unroll 1
    for (int cb = 0; cb < 2; ++cb) {
        f4 acc = *(const f4*)&bs[160 + cb * 16 + quad * 4];
        const unsigned short* wh = &Wl[(W0F + W1F + cb * 3) * FRAG];
        bf16x8 h0 = *(const bf16x8*)&wh[0];
        bf16x8 h1 = *(const bf16x8*)&wh[FRAG];
        bf16x8 h2 = *(const bf16x8*)&wh[2 * FRAG];
        acc = __builtin_amdgcn_mfma_f32_16x16x32_bf16(h0, b3f[0], acc, 0, 0, 0);
        acc = __builtin_amdgcn_mfma_f32_16x16x32_bf16(h1, b3f[1], acc, 0, 0, 0);
        acc = __builtin_amdgcn_mfma_f32_16x16x32_bf16(h2, b3f[2], acc, 0, 0, 0);
        *(f4*)&po[cb * 16 + quad * 4] = acc;
    }
}

// ---- merged projection + scan + weight-pack ----
__global__ __launch_bounds__(256) void proj_scan_kernel(
    const float* __restrict__ inp, const float* __restrict__ grid_in,
    const float* __restrict__ W0, const float* __restrict__ b0,
    const float* __restrict__ W1, const float* __restrict__ b1,
    unsigned short* __restrict__ f0b, int* __restrict__ posb,
    const int* __restrict__ counts, int* __restrict__ offsets,
    const float* __restrict__ i0W0, const float* __restrict__ i0W1,
    const float* __restrict__ i0W2, unsigned short* __restrict__ wpack0,
    const float* __restrict__ i1W0, const float* __restrict__ i1W1,
    const float* __restrict__ i1W2, unsigned short* __restrict__ wpack1)
{
    const int t = threadIdx.x;
    if (blockIdx.x == 769) { pack_weights(i0W0, i0W1, i0W2, wpack0, t); return; }
    if (blockIdx.x == 770) { pack_weights(i1W0, i1W1, i1W2, wpack1, t); return; }
    if (blockIdx.x == 768) {
        __shared__ int ws2[4], wx2[4];
        const int lane = t & 63, wave = t >> 6;
        int4 a[8];
#pragma unroll
        for (int i = 0; i < 8; ++i) a[i] = ((const int4*)counts)[t * 8 + i];
        int s = 0;
#pragma unroll
        for (int i = 0; i < 8; ++i) s += a[i].x + a[i].y + a[i].z + a[i].w;
        int x = s;
#pragma unroll
        for (int d = 1; d < 64; d <<= 1) {
            int y = __shfl_up(x, d);
            if (lane >= d) x += y;
        }
        if (lane == 63) ws2[wave] = x;
        __syncthreads();
        if (t == 0) {
            wx2[0] = 0;
            wx2[1] = ws2[0];
            wx2[2] = ws2[0] + ws2[1];
            wx2[3] = ws2[0] + ws2[1] + ws2[2];
        }
        __syncthreads();
        int base = wx2[wave] + (x - s);
#pragma unroll
        for (int i = 0; i < 8; ++i) {
            int4 c = a[i];
            int4 o;
            o.x = base; base += c.x;
            o.y = base; base += c.y;
            o.z = base; base += c.z;
            o.w = base; base += c.w;
            ((int4*)offsets)[t * 8 + i] = o;
        }
        return;
    }
    __shared__ float W0s[8 * 64];
    __shared__ float W1s[64 * OUTD];
    __shared__ float xs[32 * 8];
    __shared__ float H[32 * 64];
    const int r0 = blockIdx.x * 32;
    for (int idx = t; idx < 512; idx += 256) W0s[idx] = W0[idx];
    for (int idx = t; idx < 64 * OUTD; idx += 256) W1s[idx] = W1[idx];
    xs[t] = inp[r0 * 8 + t];
    if (t < 32) {
        int row = r0 + t, n = row / 3;
        posb[n] = pk2(grid_in[2 * n], grid_in[2 * n + 1]);  // dup writes benign
    }
    __syncthreads();
#pragma unroll 1
    for (int p = 0; p < 8; ++p) {
        int o = t + 256 * p, r = o >> 6, col = o & 63;
        float s = b0[col];
#pragma unroll
        for (int k = 0; k < 8; ++k) s += xs[r * 8 + k] * W0s[k * 64 + col];
        H[o] = gelu_f(s);
    }
    __syncthreads();
#pragma unroll 1
    for (int p = 0; p < 4; ++p) {
        int o = t + 256 * p, r = o >> 5, c = o & 31;
        float s = b1[c];
#pragma unroll 8
        for (int k = 0; k < 64; ++k) s += H[r * 64 + k] * W1s[k * OUTD + c];
        int row = r0 + r;
        int n = row / 3, v = row - n * 3;
        f0b[((size_t)(v << 13) + n) * RP + c] = f2bf(s);
    }
}

// ---- edge MLP + owner-computes segment mean ----
// 8 waves x 512 thr, PB=8 -> 1024 blocks, 4 blocks/CU = 32 waves/CU.
// Gather pipeline is 2-deep: index load (nbr_index) issued 2 iterations
// ahead, record gather (f0b) 1 ahead — the dependent index->record chain is
// never exposed in steady state.
__global__ __launch_bounds__(512, 8) void agg_kernel(
    const float* __restrict__ grid_in, const unsigned short* __restrict__ f0b,
    const int* __restrict__ posb,
    const int* __restrict__ nbr_index, const int* __restrict__ offsets,
    const int* __restrict__ counts,
    const unsigned short* __restrict__ wpack,
    const float* __restrict__ b0g, const float* __restrict__ b1g,
    const float* __restrict__ b2g,
    unsigned short* __restrict__ f1b)
{
    __shared__ __attribute__((aligned(16))) unsigned short Tb[NWAVES * 16 * TPCH];
    __shared__ __attribute__((aligned(16))) float bs[192];
    __shared__ __attribute__((aligned(16))) float accH[VARS * PB * 32];
    __shared__ int offs[PB + 1];
    __shared__ int px2b[PB];
    __shared__ float invb[PB];

    const int t = threadIdx.x;
    const int lane = t & 63, wave = t >> 6;
    const int lm = lane & 15, quad = lane >> 4;
    const int p0 = blockIdx.x * PB;
    const unsigned short* Wl = wpack + lane * 8;   // lane-major fragment base

    for (int idx = t; idx < 192; idx += NT)
        bs[idx] = (idx < 80) ? b0g[idx] : (idx < 160 ? b1g[idx - 80] : b2g[idx - 160]);
    if (t < PB) {
        offs[t] = offsets[p0 + t];
        int c = counts[p0 + t];
        invb[t] = 1.0f / (float)(c > 1 ? c : 1);
        px2b[t] = pk2(grid_in[2 * (p0 + t)], grid_in[2 * (p0 + t) + 1]);
    }
    if (t == PB) offs[PB] = offsets[p0 + PB - 1] + counts[p0 + PB - 1];
    for (int idx = t; idx < VARS * PB * 32; idx += NT) accH[idx] = 0.0f;
    __syncthreads();

    // zero persistent pad [80..96) of this wave's 16 rows (never rewritten)
    unsigned short* TbW = Tb + (wave * 16) * TPCH;
    if (lane < 32)
        *(int4*)(TbW + (lane >> 1) * TPCH + 80 + (lane & 1) * 8) = make_int4(0, 0, 0, 0);

    const int e0 = offs[0];
    const int cntT = offs[PB] - e0;
    const int Rb = VARS * cntT;
    const int nch = (Rb + 15) >> 4;

    unsigned short* Trow = TbW + lm * TPCH;

    // stage A: index fetch (key + nbr j) — issues one global load
    auto fetch_index = [&](int ch2, int& key, int& j) {
        key = -1; j = 0;
        if (ch2 < nch) {
            int myrow = (ch2 << 4) + lm;
            if (myrow < Rb) {
                int myv = (myrow >= 2 * cntT) ? 2 : ((myrow >= cntT) ? 1 : 0);
                int e = e0 + myrow - myv * cntT;
                int lp = 0;
#pragma unroll
                for (int l = 1; l < PB; ++l) lp += (e >= offs[l]);
                key = myv * PB + lp;
                j = nbr_index[e];
            }
        }
    };
    // stage B: record gather — j must be resident (loaded 1 iteration earlier)
    auto fetch_record = [&](int key, int j, int4& feats, int4& posf) {
        feats = make_int4(0, 0, 0, 0); posf = make_int4(0, 0, 0, 0);
        if (key >= 0) {
            int v = key >> 3, lp = key & 7;   // PB == 8
            feats = ((const int4*)(f0b + ((size_t)(v << 13) + j) * RP))[quad];
            if (quad == 0) posf = make_int4(posb[j], px2b[lp], 0, 0);
        }
    };

    int keyA, jA, keyB, jB;
    fetch_index(wave, keyA, jA);
    fetch_index(wave + NWAVES, keyB, jB);
    int4 featsA, posfA;
    fetch_record(keyA, jA, featsA, posfA);

    for (int ch = wave; ch < nch; ch += NWAVES) {
        int ckey = keyA; int4 cf = featsA, cp = posfA;
        keyA = keyB; jA = jB;
        fetch_index(ch + 2 * NWAVES, keyB, jB);       // index 2 ahead
        fetch_record(keyA, jA, featsA, posfA);        // record 1 ahead
        mlp_chunk(cf, cp, Trow, Wl, bs, lm, quad);
        // keyed reduction of this wave's 16 rows into block accumulator
        int col = lane & 31, eo = lane >> 5;
#pragma unroll 1
        for (int e2 = eo; e2 < 16; e2 += 2) {
            int k = __shfl(ckey, e2);
            if (k >= 0)
                atomicAdd(&accH[k * 32 + col], ((const float*)(TbW + e2 * TPCH))[col]);
        }
    }
    __syncthreads();
    for (int idx = t; idx < VARS * PB * OUTD; idx += NT) {
        int key = idx >> 5, c = idx & 31;
        int v = key >> 3, lp = key & 7;     // PB == 8
        size_t rec = ((size_t)(v << 13) + p0 + lp) * RP;
        float val = accH[key * 32 + c] * invb[lp] + bf2f(f0b[rec + c]);
        f1b[rec + c] = f2bf(val);
    }
}

// ---- kNN MLP + mean over K ----
// 256 thr / 4 waves, LPTS=4 -> 512 blocks, 8 blocks/CU = 32 waves/CU,
// 2 chunks/wave.
__global__ __launch_bounds__(256, 8) void last_kernel(
    const unsigned short* __restrict__ f1b, const int* __restrict__ posb,
    const float* __restrict__ grid_out,
    const int* __restrict__ nbr_last,
    const unsigned short* __restrict__ wpack,
    const float* __restrict__ b0g, const float* __restrict__ b1g,
    const float* __restrict__ b2g,
    float* __restrict__ out)
{
    __shared__ __attribute__((aligned(16))) unsigned short Tb[NWL * 16 * TPCH];
    __shared__ __attribute__((aligned(16))) float bs[192];
    __shared__ __attribute__((aligned(16))) float accH[LPTS * VARS * 32];
    __shared__ int pxo2b[LPTS];

    const int t = threadIdx.x;
    const int lane = t & 63, wave = t >> 6;
    const int lm = lane & 15, quad = lane >> 4;
    const int m0 = blockIdx.x * LPTS;
    const unsigned short* Wl = wpack + lane * 8;   // lane-major fragment base

    for (int idx = t; idx < 192; idx += NTL)
        bs[idx] = (idx < 80) ? b0g[idx] : (idx < 160 ? b1g[idx - 80] : b2g[idx - 160]);
    if (t < LPTS)
        pxo2b[t] = pk2(grid_out[2 * (m0 + t)], grid_out[2 * (m0 + t) + 1]);
    for (int idx = t; idx < LPTS * VARS * 32; idx += NTL) accH[idx] = 0.0f;
    __syncthreads();
    unsigned short* TbW = Tb + (wave * 16) * TPCH;
    if (lane < 32)
        *(int4*)(TbW + (lane >> 1) * TPCH + 80 + (lane & 1) * 8) = make_int4(0, 0, 0, 0);

    const int Rb = LPTS * VARS * KLAST;   // 120
    const int nch = (Rb + 15) >> 4;       // 8
    unsigned short* Trow = TbW + lm * TPCH;

    auto fetch_index = [&](int ch2, int& key, int& j) {
        key = -1; j = 0;
        if (ch2 < nch) {
            int myrow = (ch2 << 4) + lm;
            if (myrow < Rb) {
                int lp = myrow / 30, rr = myrow - lp * 30;
                int v = rr / KLAST, kk = rr - v * KLAST;
                j = nbr_last[(m0 + lp) * KLAST + kk];
                key = lp * VARS + v;
            }
        }
    };
    auto fetch_record = [&](int key, int j, int4& feats, int4& posf) {
        feats = make_int4(0, 0, 0, 0); posf = make_int4(0, 0, 0, 0);
        if (key >= 0) {
            int lp = key / VARS, v = key - lp * VARS;
            feats = ((const int4*)(f1b + ((size_t)(v << 13) + j) * RP))[quad];
            if (quad == 0) posf = make_int4(posb[j], pxo2b[lp], 0, 0);
        }
    };

    int keyA, jA, keyB, jB;
    fetch_index(wave, keyA, jA);
    fetch_index(wave + NWL, keyB, jB);
    int4 featsA, posfA;
    fetch_record(keyA, jA, featsA, posfA);

    for (int ch = wave; ch < nch; ch += NWL) {
        int ckey = keyA; int4 cf = featsA, cp = posfA;
        keyA = keyB; jA = jB;
        fetch_index(ch + 2 * NWL, keyB, jB);
        fetch_record(keyA, jA, featsA, posfA);
        mlp_chunk(cf, cp, Trow, Wl, bs, lm, quad);
        int col = lane & 31, eo = lane >> 5;
#pragma unroll 1
        for (int e2 = eo; e2 < 16; e2 += 2) {
            int k = __shfl(ckey, e2);
            if (k >= 0)
                atomicAdd(&accH[k * 32 + col], ((const float*)(TbW + e2 * TPCH))[col]);
        }
    }
    __syncthreads();
    for (int idx = t; idx < LPTS * VARS * OUTD; idx += NTL) {
        int key = idx >> 5, c = idx & 31;
        int lp = key / VARS, v = key - lp * VARS;
        out[((size_t)(m0 + lp) * VARS + v) * OUTD + c] = accH[key * 32 + c] * (1.0f / KLAST);
    }
}

extern "C" void kernel_launch(void* const* d_in, const int* in_sizes, int n_in,
                              void* d_out, int out_size, void* d_ws, size_t ws_size,
                              hipStream_t stream) {
    const float* inp      = (const float*)d_in[0];
    const float* grid_in  = (const float*)d_in[1];
    const float* grid_out = (const float*)d_in[2];
    const float* pW0 = (const float*)d_in[3];
    const float* pb0 = (const float*)d_in[4];
    const float* pW1 = (const float*)d_in[5];
    const float* pb1 = (const float*)d_in[6];
    const float* i0W0 = (const float*)d_in[7];
    const float* i0b0 = (const float*)d_in[8];
    const float* i0W1 = (const float*)d_in[9];
    const float* i0b1 = (const float*)d_in[10];
    const float* i0W2 = (const float*)d_in[11];
    const float* i0b2 = (const float*)d_in[12];
    const float* i1W0 = (const float*)d_in[13];
    const float* i1b0 = (const float*)d_in[14];
    const float* i1W1 = (const float*)d_in[15];
    const float* i1b1 = (const float*)d_in[16];
    const float* i1W2 = (const float*)d_in[17];
    const float* i1b2 = (const float*)d_in[18];
    const int* nbr_index  = (const int*)d_in[19];
    const int* nbr_counts = (const int*)d_in[21];
    const int* nbr_last   = (const int*)d_in[22];

    unsigned short* f0b = (unsigned short*)d_ws;                      // 3*8192*32 bf16
    unsigned short* f1b = f0b + (size_t)VARS * N_PTS * RP;            // 3*8192*32 bf16
    int* offsets = (int*)(f1b + (size_t)VARS * N_PTS * RP);           // N ints
    int* posb    = offsets + N_PTS;                                   // N ints (bf16x2)
    unsigned short* wpack0 = (unsigned short*)(posb + N_PTS);         // 15872 bf16
    unsigned short* wpack1 = wpack0 + WPACK;                          // 15872 bf16

    proj_scan_kernel<<<771, 256, 0, stream>>>(inp, grid_in, pW0, pb0, pW1, pb1,
                                              f0b, posb, nbr_counts, offsets,
                                              i0W0, i0W1, i0W2, wpack0,
                                              i1W0, i1W1, i1W2, wpack1);
    agg_kernel<<<N_PTS / PB, NT, 0, stream>>>(grid_in, f0b, posb, nbr_index, offsets,
                                              nbr_counts, wpack0,
                                              i0b0, i0b1, i0b2, f1b);
    last_kernel<<<M_PTS / LPTS, NTL, 0, stream>>>(f1b, posb, grid_out, nbr_last, wpack1,
                                                  i1b0, i1b1, i1b2,
                                                  (float*)d_out);
}